// Round 5
// baseline (1015.362 us; speedup 1.0000x reference)
//
#include <hip/hip_runtime.h>
#include <cfloat>
#include <cmath>

typedef short short8 __attribute__((ext_vector_type(8)));
typedef unsigned short ushort8 __attribute__((ext_vector_type(8)));
typedef float f32x16 __attribute__((ext_vector_type(16)));

#define K_CODES 8192
#define DIM 256
#define NQ_TOTAL 32768
#define CSPLIT 8
#define CT_PER_BLOCK 8    /* 8 x 128-code tiles = 1024 codes per block */
#define TOPN 8

/* ws layout (byte offsets) */
#define WS_COUNTS 0          /* int[8192]                  32 KB (zeroed) */
#define WS_LOSSQ  32768      /* float[32768]              128 KB */
#define WS_NORMS  163840     /* float[8192]                32 KB */
#define WS_PVAL   196608     /* float[8*32768*8]            8 MB */
#define WS_PIDX   8585216    /* int  [8*32768*8]            8 MB */
#define WS_ET     16973824   /* float[8192*256]             8 MB */
#define WS_AHI    25362432   /* ushort[8192*256]            4 MB */
#define WS_BHI    29556736   /* ushort[32768*256]          16 MB */

__device__ inline unsigned short f32_to_bf16_rne(float x) {
    unsigned u = __builtin_bit_cast(unsigned, x);
    unsigned r = u + 0x7FFFu + ((u >> 16) & 1u);
    return (unsigned short)(r >> 16);
}

// sorted-descending top-N insert with carry-down (caller guards v > tv[N-1])
__device__ inline void insN(float v, int c, float* tv, int* ti) {
#pragma unroll
    for (int j = 0; j < TOPN; ++j) {
        bool g = v > tv[j];
        float ov = tv[j]; int oc = ti[j];
        tv[j] = g ? v : ov;  ti[j] = g ? c : oc;
        v = g ? ov : v;      c = g ? oc : c;
    }
}

// ---------------------------------------------------------------- norms (fp32, exact)
__global__ __launch_bounds__(256) void norms_kernel(const float* __restrict__ E,
                                                    float* __restrict__ norms) {
    int k = blockIdx.x * 256 + threadIdx.x;
    float s = 0.f;
#pragma unroll 8
    for (int d = 0; d < DIM; ++d) { float v = E[(size_t)d * K_CODES + k]; s += v * v; }
    norms[k] = s;
}

// ---------------------------------------------------------------- pack X -> frag-linear bf16
__global__ __launch_bounds__(256) void pack_X(const float* __restrict__ X,
                                              unsigned short* __restrict__ Bhi) {
    int id = blockIdx.x * 256 + threadIdx.x;      // 1048576 total
    int q = id >> 5, db = id & 31;
    const float* src = X + (size_t)q * DIM + db * 8;
    float4 a = *(const float4*)src, b = *(const float4*)(src + 4);
    float xs[8] = {a.x, a.y, a.z, a.w, b.x, b.y, b.z, b.w};
    ushort8 vh;
#pragma unroll
    for (int i = 0; i < 8; ++i) vh[i] = f32_to_bf16_rne(xs[i]);
    int qt = q >> 7, nt = (q >> 5) & 3, lq = q & 31, s = db >> 1, hh = db & 1;
    int lane = lq + 32 * hh;
    size_t chunk = ((((size_t)qt * 16 + s) * 4 + nt) * 64 + lane) * 8;
    *(ushort8*)&Bhi[chunk] = vh;
}

// ---------------------------------------------------------------- pack E -> A frags + fp32 E^T
__global__ __launch_bounds__(256) void pack_E(const float* __restrict__ E,
                                              unsigned short* __restrict__ Ahi,
                                              float* __restrict__ ET) {
    int id = blockIdx.x * 256 + threadIdx.x;      // 262144 total
    int db = id >> 13, c = id & 8191;
    float xs[8];
#pragma unroll
    for (int j = 0; j < 8; ++j) xs[j] = E[(size_t)(db * 8 + j) * K_CODES + c];
    float4 f0 = {xs[0], xs[1], xs[2], xs[3]}, f1 = {xs[4], xs[5], xs[6], xs[7]};
    *(float4*)&ET[(size_t)c * DIM + db * 8]     = f0;
    *(float4*)&ET[(size_t)c * DIM + db * 8 + 4] = f1;
    ushort8 vh;
#pragma unroll
    for (int j = 0; j < 8; ++j) vh[j] = f32_to_bf16_rne(xs[j]);
    int ct = c >> 7, mt = (c >> 5) & 3, lc = c & 31, s = db >> 1, hh = db & 1;
    int lane = lc + 32 * hh;
    size_t chunk = ((((size_t)ct * 16 + s) * 4 + mt) * 64 + lane) * 8;
    *(ushort8*)&Ahi[chunk] = vh;
}

// ---------------------------------------------------------------- MFMA argmax (single bf16 product)
// grid (CSPLIT, 256 query-tiles), 256 threads = 4 waves.
// Block tile: 128 codes x 128 queries per ctl; wave tile 64x64 (2x2 acc of 32x32).
// B (128 queries, full D) persistent in LDS (64 KB, staged once);
// A streams in BK=64 stages of 16 KB through a 2-barrier loop.
__global__ __launch_bounds__(256, 2) void argmax_mfma(
        const unsigned short* __restrict__ Ahi, const unsigned short* __restrict__ Bhi,
        const float* __restrict__ norms,
        float* __restrict__ pval, int* __restrict__ pidx) {
    __shared__ __align__(16) char smem[81920];     // B 64KB | A-stage 16KB
    unsigned short* Bs = (unsigned short*)smem;                // 32768 shorts
    unsigned short* As = (unsigned short*)(smem + 65536);      // 8192 shorts
    float (*pvs)[128][TOPN] = (float (*)[128][TOPN])smem;      // merge: union into B region
    int   (*pis)[128][TOPN] = (int (*)[128][TOPN])(smem + 16384);

    const int tid = threadIdx.x;
    const int lane = tid & 63, w = tid >> 6;
    const int wm = w & 1, wn = w >> 1;             // wave -> (code half, query half)
    const int h = lane >> 5;
    const int cs = blockIdx.x, qt = blockIdx.y;

    // ---- stage B once: 64 x 1KB chunks (16 per wave), full D for 128 queries
#pragma unroll
    for (int i = 0; i < 16; ++i) {
        const int g = w * 16 + i, s = g >> 2, nt = g & 3;
        const unsigned short* src = Bhi + ((((size_t)qt * 16 + s) * 4 + nt) * 64 + lane) * 8;
        __builtin_amdgcn_global_load_lds(
            (const __attribute__((address_space(1))) unsigned int*)src,
            (__attribute__((address_space(3))) unsigned int*)(Bs + (s * 4 + nt) * 512), 16, 0, 0);
    }
    __syncthreads();

    float tv[2][TOPN]; int ti[2][TOPN];
#pragma unroll
    for (int n2 = 0; n2 < 2; ++n2)
#pragma unroll
        for (int j = 0; j < TOPN; ++j) { tv[n2][j] = -FLT_MAX; ti[n2][j] = 0; }

    for (int ctl = 0; ctl < CT_PER_BLOCK; ++ctl) {
        const int ct128 = cs * CT_PER_BLOCK + ctl;

        f32x16 acc[2][2];
#pragma unroll
        for (int mt = 0; mt < 2; ++mt)
#pragma unroll
            for (int n2 = 0; n2 < 2; ++n2)
#pragma unroll
                for (int r = 0; r < 16; ++r) acc[mt][n2][r] = 0.f;

        for (int st = 0; st < 4; ++st) {           // D-loop: 4 stages x BK=64
            __syncthreads();                       // previous stage's A-readers done
#pragma unroll
            for (int i = 0; i < 4; ++i) {          // A: 16 x 1KB chunks (4 per wave)
                const int g = w * 4 + i, s2 = g >> 2, mtg = g & 3;
                const unsigned short* src =
                    Ahi + ((((size_t)ct128 * 16 + st * 4 + s2) * 4 + mtg) * 64 + lane) * 8;
                __builtin_amdgcn_global_load_lds(
                    (const __attribute__((address_space(1))) unsigned int*)src,
                    (__attribute__((address_space(3))) unsigned int*)(As + (s2 * 4 + mtg) * 512),
                    16, 0, 0);
            }
            __syncthreads();                       // vmcnt drained -> LDS visible
#pragma unroll
            for (int s2 = 0; s2 < 4; ++s2) {
                short8 af[2], bf[2];
#pragma unroll
                for (int mt = 0; mt < 2; ++mt)
                    af[mt] = *(const short8*)&As[(s2 * 4 + wm * 2 + mt) * 512 + lane * 8];
#pragma unroll
                for (int n2 = 0; n2 < 2; ++n2)
                    bf[n2] = *(const short8*)&Bs[((st * 4 + s2) * 4 + wn * 2 + n2) * 512 + lane * 8];
#pragma unroll
                for (int mt = 0; mt < 2; ++mt)
#pragma unroll
                    for (int n2 = 0; n2 < 2; ++n2)
                        acc[mt][n2] = __builtin_amdgcn_mfma_f32_32x32x16_bf16(
                            af[mt], bf[n2], acc[mt][n2], 0, 0, 0);
            }
        }

        // epilogue: fold exact norms, guarded top-8 insert (codes ascending)
        const int cbase = ct128 * 128 + wm * 64;
#pragma unroll
        for (int mt = 0; mt < 2; ++mt) {
            const int cb0 = cbase + mt * 32 + 4 * h;
#pragma unroll
            for (int r = 0; r < 16; ++r) {
                const int code = cb0 + (r & 3) + 8 * (r >> 2);
                const float nrm = norms[code];
#pragma unroll
                for (int n2 = 0; n2 < 2; ++n2) {
                    float v = 2.f * acc[mt][n2][r] - nrm;
                    if (v > tv[n2][TOPN - 1]) insN(v, code, tv[n2], ti[n2]);
                }
            }
        }
    }

    __syncthreads();                               // all LDS reads done before merge aliases B
    const int slot = wm * 2 + h;
#pragma unroll
    for (int n2 = 0; n2 < 2; ++n2) {
        const int ql = wn * 64 + n2 * 32 + (lane & 31);
#pragma unroll
        for (int j = 0; j < TOPN; ++j) { pvs[slot][ql][j] = tv[n2][j]; pis[slot][ql][j] = ti[n2][j]; }
    }
    __syncthreads();
    if (tid < 128) {
        float mv[TOPN]; int mi[TOPN];
#pragma unroll
        for (int j = 0; j < TOPN; ++j) { mv[j] = -FLT_MAX; mi[j] = 0; }
#pragma unroll
        for (int sl = 0; sl < 4; ++sl)
#pragma unroll
            for (int j = 0; j < TOPN; ++j) {
                float v = pvs[sl][tid][j]; int c = pis[sl][tid][j];
                if (v > mv[TOPN - 1]) insN(v, c, mv, mi);
            }
        size_t o = ((size_t)cs * NQ_TOTAL + qt * 128 + tid) * TOPN;
#pragma unroll
        for (int j = 0; j < TOPN; ++j) { pval[o + j] = mv[j]; pidx[o + j] = mi[j]; }
    }
}

// ---------------------------------------------------------------- candidate merge + exact rescore
// one wave per query; 64 candidates (8 slices x top-8) mapped 1:1 to lanes;
// 8 rounds of wave-argmax pick approx top-8; exact fp32 rescore picks the winner.
__global__ __launch_bounds__(256) void finalize_q(
        const float* __restrict__ X, const float* __restrict__ ET,
        const float* __restrict__ norms, const float* __restrict__ pval,
        const int* __restrict__ pidx, float* __restrict__ outq,
        float* __restrict__ out_idx_f, float* __restrict__ loss_q,
        int* __restrict__ counts) {
    const int lane = threadIdx.x & 63, w = threadIdx.x >> 6;
    const int q = blockIdx.x * 4 + w;
    float4 x4 = *(const float4*)&X[(size_t)q * DIM + lane * 4];

    // lane -> candidate (slice p = lane>>3, rank j = lane&7)
    const int p = lane >> 3, j = lane & 7;
    size_t off = ((size_t)p * NQ_TOTAL + q) * TOPN + j;
    float wv = pval[off];
    int   wc = pidx[off];

    int kc[TOPN];
#pragma unroll
    for (int t = 0; t < TOPN; ++t) {
        float v = wv; int src = lane;
#pragma unroll
        for (int o = 1; o < 64; o <<= 1) {
            float ov = __shfl_xor(v, o); int os = __shfl_xor(src, o);
            bool take = (ov > v) || (ov == v && os < src);
            v = take ? ov : v; src = take ? os : src;
        }
        kc[t] = __shfl(wc, src);
        if (lane == src) wv = -FLT_MAX;     // remove winner
    }

    float sb = -FLT_MAX; int kb = 0; float4 eb = x4;
#pragma unroll
    for (int t = 0; t < TOPN; ++t) {
        int k = kc[t];
        float4 e4 = *(const float4*)&ET[(size_t)k * DIM + lane * 4];
        float pr = x4.x * e4.x + x4.y * e4.y + x4.z * e4.z + x4.w * e4.w;
#pragma unroll
        for (int o = 1; o < 64; o <<= 1) pr += __shfl_xor(pr, o);
        float s = 2.f * pr - norms[k];
        bool better = (s > sb) || (s == sb && k < kb);
        if (better) { sb = s; kb = k; eb = e4; }
    }
    float4 d4 = {eb.x - x4.x, eb.y - x4.y, eb.z - x4.z, eb.w - x4.w};
    float4 o4 = {x4.x + d4.x, x4.y + d4.y, x4.z + d4.z, x4.w + d4.w};
    *(float4*)&outq[(size_t)q * DIM + lane * 4] = o4;
    float l = d4.x * d4.x + d4.y * d4.y + d4.z * d4.z + d4.w * d4.w;
#pragma unroll
    for (int o = 1; o < 64; o <<= 1) l += __shfl_xor(l, o);
    if (lane == 0) {
        out_idx_f[q] = (float)kb;
        loss_q[q] = l;
        atomicAdd(&counts[kb], 1);
    }
}

// ---------------------------------------------------------------- scalars
__global__ __launch_bounds__(256) void final_scalars(
        const int* __restrict__ counts, const float* __restrict__ loss_q,
        float* __restrict__ out_sc) {
    int t = threadIdx.x;
    float ls = 0.f;
    for (int i = t; i < NQ_TOTAL; i += 256) ls += loss_q[i];
    float ent = 0.f;
    for (int k = t; k < K_CODES; k += 256) {
        float p = (float)counts[k] / (float)NQ_TOTAL;
        ent -= p * logf(p + 1e-10f);
    }
#pragma unroll
    for (int o = 1; o < 64; o <<= 1) { ls += __shfl_xor(ls, o); ent += __shfl_xor(ent, o); }
    __shared__ float rl[4], re[4];
    if ((t & 63) == 0) { rl[t >> 6] = ls; re[t >> 6] = ent; }
    __syncthreads();
    if (t == 0) {
        float L = rl[0] + rl[1] + rl[2] + rl[3];
        float Ee = re[0] + re[1] + re[2] + re[3];
        float mse = L / (float)((size_t)NQ_TOTAL * DIM);
        out_sc[0] = 1.1f * mse;                         // e_latent + 0.1*q_latent
        out_sc[1] = -0.1f * (Ee / logf((float)K_CODES));
    }
}

extern "C" void kernel_launch(void* const* d_in, const int* in_sizes, int n_in,
                              void* d_out, int out_size, void* d_ws, size_t ws_size,
                              hipStream_t stream) {
    const float* X = (const float*)d_in[0];   // [32768, 256] fp32
    const float* E = (const float*)d_in[1];   // [256, 8192]  fp32

    float* out       = (float*)d_out;
    float* outq      = out;                           // 8388608
    float* out_idx_f = out + (size_t)NQ_TOTAL * DIM;  // 32768 (indices as f32)
    float* out_sc    = out_idx_f + NQ_TOTAL;          // 2 scalars

    char* ws = (char*)d_ws;
    int*            counts = (int*)(ws + WS_COUNTS);
    float*          loss_q = (float*)(ws + WS_LOSSQ);
    float*          norms  = (float*)(ws + WS_NORMS);
    float*          pval   = (float*)(ws + WS_PVAL);
    int*            pidx   = (int*)(ws + WS_PIDX);
    float*          ET     = (float*)(ws + WS_ET);
    unsigned short* Ahi    = (unsigned short*)(ws + WS_AHI);
    unsigned short* Bhi    = (unsigned short*)(ws + WS_BHI);

    hipMemsetAsync(counts, 0, K_CODES * sizeof(int), stream);
    norms_kernel<<<K_CODES / 256, 256, 0, stream>>>(E, norms);
    pack_X<<<(NQ_TOTAL * 32) / 256, 256, 0, stream>>>(X, Bhi);
    pack_E<<<(K_CODES * 32) / 256, 256, 0, stream>>>(E, Ahi, ET);
    argmax_mfma<<<dim3(CSPLIT, NQ_TOTAL / 128), 256, 0, stream>>>(Ahi, Bhi, norms, pval, pidx);
    finalize_q<<<NQ_TOTAL / 4, 256, 0, stream>>>(X, ET, norms, pval, pidx, outq, out_idx_f, loss_q, counts);
    final_scalars<<<1, 256, 0, stream>>>(counts, loss_q, out_sc);
}

// Round 6
// 516.396 us; speedup vs baseline: 1.9662x; 1.9662x over previous
//
#include <hip/hip_runtime.h>
#include <cfloat>
#include <cmath>

typedef short short8 __attribute__((ext_vector_type(8)));
typedef unsigned short ushort8 __attribute__((ext_vector_type(8)));
typedef float f32x16 __attribute__((ext_vector_type(16)));

#define K_CODES 8192
#define DIM 256
#define NQ_TOTAL 32768
#define CSPLIT 8
#define NSTAGE 17          /* 16 data stages + 1 norm stage */
#define NSTEP 136          /* 8 code-tiles x 17 stages */
#define PDEPTH 8           /* A-pipeline depth (register slots) */
#define TOPS 4             /* per-slice top-N stored */

/* ws layout (byte offsets) */
#define WS_COUNTS 0          /* int[8192]            32 KB (zeroed) */
#define WS_LOSSQ  32768      /* float[32768]        128 KB */
#define WS_NORMS  163840     /* float[8192]          32 KB */
#define WS_PVAL   196608     /* float[8*32768*4]      4 MB */
#define WS_PIDX   4390912    /* int  [8*32768*4]      4 MB */
#define WS_ET     8585216    /* float[8192*256]       8 MB */
#define WS_AHI    16973824   /* ushort[64*17*4*64*8]  4.25 MB */
#define WS_BHI    21430272   /* ushort[256*17*4*64*8] 17 MB */

__device__ inline unsigned short f32_to_bf16_rne(float x) {
    unsigned u = __builtin_bit_cast(unsigned, x);
    unsigned r = u + 0x7FFFu + ((u >> 16) & 1u);
    return (unsigned short)(r >> 16);
}
__device__ inline float bf16_to_f32(unsigned short hh) {
    unsigned u = ((unsigned)hh) << 16;
    return __builtin_bit_cast(float, u);
}

// sorted-descending top-4 insert with carry-down (caller guards v > tv[3])
__device__ inline void ins4(float v, int c, float* tv, int* ti) {
#pragma unroll
    for (int j = 0; j < TOPS; ++j) {
        bool g = v > tv[j];
        float ov = tv[j]; int oc = ti[j];
        tv[j] = g ? v : ov;  ti[j] = g ? c : oc;
        v = g ? ov : v;      c = g ? oc : c;
    }
}

// ---------------------------------------------------------------- norms (fp32, exact)
__global__ __launch_bounds__(256) void norms_kernel(const float* __restrict__ E,
                                                    float* __restrict__ norms) {
    int k = blockIdx.x * 256 + threadIdx.x;
    float s = 0.f;
#pragma unroll 8
    for (int d = 0; d < DIM; ++d) { float v = E[(size_t)d * K_CODES + k]; s += v * v; }
    norms[k] = s;
}

// ---------------------------------------------------------------- pack X -> frag-linear bf16 (17-stage stride)
__global__ __launch_bounds__(256) void pack_X(const float* __restrict__ X,
                                              unsigned short* __restrict__ Bhi) {
    int id = blockIdx.x * 256 + threadIdx.x;      // 1048576 total
    int q = id >> 5, db = id & 31;
    const float* src = X + (size_t)q * DIM + db * 8;
    float4 a = *(const float4*)src, b = *(const float4*)(src + 4);
    float xs[8] = {a.x, a.y, a.z, a.w, b.x, b.y, b.z, b.w};
    ushort8 vh;
#pragma unroll
    for (int i = 0; i < 8; ++i) vh[i] = f32_to_bf16_rne(xs[i]);
    int qt = q >> 7, nt = (q >> 5) & 3, lq = q & 31, s = db >> 1, hh = db & 1;
    int lane = lq + 32 * hh;
    size_t chunk = ((((size_t)qt * NSTAGE + s) * 4 + nt) * 64 + lane) * 8;
    *(ushort8*)&Bhi[chunk] = vh;
}

// ---------------------------------------------------------------- B norm-stage: -0.5 at k=0,1
__global__ __launch_bounds__(256) void pack_Bx(unsigned short* __restrict__ Bhi) {
    int id = blockIdx.x * 256 + threadIdx.x;      // 65536 total
    int lane = id & 63, nt = (id >> 6) & 3, qt = id >> 8;
    ushort8 v = {0, 0, 0, 0, 0, 0, 0, 0};
    if (lane < 32) { v[0] = 0xBF00; v[1] = 0xBF00; }   // bf16(-0.5)
    size_t chunk = ((((size_t)qt * NSTAGE + 16) * 4 + nt) * 64 + lane) * 8;
    *(ushort8*)&Bhi[chunk] = v;
}

// ---------------------------------------------------------------- pack E -> A frags + fp32 E^T
__global__ __launch_bounds__(256) void pack_E(const float* __restrict__ E,
                                              unsigned short* __restrict__ Ahi,
                                              float* __restrict__ ET) {
    int id = blockIdx.x * 256 + threadIdx.x;      // 262144 total
    int db = id >> 13, c = id & 8191;
    float xs[8];
#pragma unroll
    for (int j = 0; j < 8; ++j) xs[j] = E[(size_t)(db * 8 + j) * K_CODES + c];
    float4 f0 = {xs[0], xs[1], xs[2], xs[3]}, f1 = {xs[4], xs[5], xs[6], xs[7]};
    *(float4*)&ET[(size_t)c * DIM + db * 8]     = f0;
    *(float4*)&ET[(size_t)c * DIM + db * 8 + 4] = f1;
    ushort8 vh;
#pragma unroll
    for (int j = 0; j < 8; ++j) vh[j] = f32_to_bf16_rne(xs[j]);
    int ct = c >> 7, mt = (c >> 5) & 3, lc = c & 31, s = db >> 1, hh = db & 1;
    int lane = lc + 32 * hh;
    size_t chunk = ((((size_t)ct * NSTAGE + s) * 4 + mt) * 64 + lane) * 8;
    *(ushort8*)&Ahi[chunk] = vh;
}

// ---------------------------------------------------------------- A norm-stage: nrm_hi, nrm_lo at k=0,1
__global__ __launch_bounds__(256) void pack_Ax(const float* __restrict__ norms,
                                               unsigned short* __restrict__ Ahi) {
    int id = blockIdx.x * 256 + threadIdx.x;      // 16384 total
    int lane = id & 63, mt = (id >> 6) & 3, ct = id >> 8;
    ushort8 v = {0, 0, 0, 0, 0, 0, 0, 0};
    if (lane < 32) {
        float nrm = norms[ct * 128 + mt * 32 + lane];
        unsigned short hi = f32_to_bf16_rne(nrm);
        unsigned short lo = f32_to_bf16_rne(nrm - bf16_to_f32(hi));
        v[0] = hi; v[1] = lo;
    }
    size_t chunk = ((((size_t)ct * NSTAGE + 16) * 4 + mt) * 64 + lane) * 8;
    *(ushort8*)&Ahi[chunk] = v;
}

// ---------------------------------------------------------------- MFMA argmax — barrier-free K-loop
// grid (CSPLIT, 256 query-tiles), 256 threads = 4 waves, wave tile 64 codes x 64 queries.
// B (128 queries, 17 stages incl. norm stage) persistent in LDS; A streams
// global->VGPR via a depth-8 rolling pipeline; norms folded by stage 16; acc = score/2.
__global__ __launch_bounds__(256, 2) void argmax_mfma(
        const unsigned short* __restrict__ Ahi, const unsigned short* __restrict__ Bhi,
        float* __restrict__ pval, int* __restrict__ pidx) {
    __shared__ __align__(16) char smem[69632];                 // B: 17*4*512 shorts
    unsigned short* Bs = (unsigned short*)smem;
    float (*pvs)[128][TOPS] = (float (*)[128][TOPS])smem;      // merge unions into B region
    int   (*pis)[128][TOPS] = (int (*)[128][TOPS])(smem + 16384);

    const int tid = threadIdx.x;
    const int lane = tid & 63, w = tid >> 6;
    const int wm = w & 1, wn = w >> 1;             // wave -> (code half, query half)
    const int h = lane >> 5;
    const int cs = blockIdx.x, qt = blockIdx.y;

    // ---- stage B once: 68 x 1KB chunks (17 per wave)
#pragma unroll
    for (int i = 0; i < NSTAGE; ++i) {
        const int g = w * NSTAGE + i, s = g >> 2, nt = g & 3;
        const unsigned short* src = Bhi + ((((size_t)qt * NSTAGE + s) * 4 + nt) * 64 + lane) * 8;
        __builtin_amdgcn_global_load_lds(
            (const __attribute__((address_space(1))) unsigned int*)src,
            (__attribute__((address_space(3))) unsigned int*)(Bs + (s * 4 + nt) * 512), 16, 0, 0);
    }

    // A base for this wave (step stride = 2048 shorts = 4 KB)
    const unsigned short* Ab = Ahi + (((size_t)cs * NSTEP * 4 + wm * 2) * 64 + lane) * 8;

    // prime the A register pipeline (in flight during B staging)
    short8 ap[PDEPTH][2];
#pragma unroll
    for (int p = 0; p < PDEPTH; ++p) {
        ap[p][0] = *(const short8*)(Ab + p * 2048);
        ap[p][1] = *(const short8*)(Ab + p * 2048 + 512);
    }
    __syncthreads();                               // B visible (drains prime loads too; one-time)

    float tv[2][TOPS]; int ti[2][TOPS];
#pragma unroll
    for (int n2 = 0; n2 < 2; ++n2)
#pragma unroll
        for (int j = 0; j < TOPS; ++j) { tv[n2][j] = -FLT_MAX; ti[n2][j] = 0; }

    f32x16 acc[2][2];
#pragma unroll
    for (int mt = 0; mt < 2; ++mt)
#pragma unroll
        for (int n2 = 0; n2 < 2; ++n2)
#pragma unroll
            for (int r = 0; r < 16; ++r) acc[mt][n2][r] = 0.f;

#pragma unroll
    for (int t = 0; t < NSTEP; ++t) {
        const int s = t % NSTAGE, slot = t % PDEPTH;
        short8 a0 = ap[slot][0], a1 = ap[slot][1];
        if (t + PDEPTH < NSTEP) {                  // refill slot for step t+8
            ap[slot][0] = *(const short8*)(Ab + (t + PDEPTH) * 2048);
            ap[slot][1] = *(const short8*)(Ab + (t + PDEPTH) * 2048 + 512);
        }
        short8 b0 = *(const short8*)&Bs[((s * 4 + wn * 2 + 0) * 512) + lane * 8];
        short8 b1 = *(const short8*)&Bs[((s * 4 + wn * 2 + 1) * 512) + lane * 8];
        acc[0][0] = __builtin_amdgcn_mfma_f32_32x32x16_bf16(a0, b0, acc[0][0], 0, 0, 0);
        acc[0][1] = __builtin_amdgcn_mfma_f32_32x32x16_bf16(a0, b1, acc[0][1], 0, 0, 0);
        acc[1][0] = __builtin_amdgcn_mfma_f32_32x32x16_bf16(a1, b0, acc[1][0], 0, 0, 0);
        acc[1][1] = __builtin_amdgcn_mfma_f32_32x32x16_bf16(a1, b1, acc[1][1], 0, 0, 0);

        if (s == NSTAGE - 1) {                     // tile done: acc = score/2, norms folded
            const int cbase = (cs * 8 + t / NSTAGE) * 128 + wm * 64;
#pragma unroll
            for (int mt = 0; mt < 2; ++mt) {
                const int cb0 = cbase + mt * 32 + 4 * h;
#pragma unroll
                for (int r = 0; r < 16; ++r) {
                    const int code = cb0 + (r & 3) + 8 * (r >> 2);
#pragma unroll
                    for (int n2 = 0; n2 < 2; ++n2) {
                        float v = acc[mt][n2][r];
                        if (v > tv[n2][TOPS - 1]) ins4(v, code, tv[n2], ti[n2]);
                        acc[mt][n2][r] = 0.f;
                    }
                }
            }
        }
    }

    __syncthreads();                               // all B reads done before merge aliases B
    const int slot4 = wm * 2 + h;
#pragma unroll
    for (int n2 = 0; n2 < 2; ++n2) {
        const int ql = wn * 64 + n2 * 32 + (lane & 31);
#pragma unroll
        for (int j = 0; j < TOPS; ++j) { pvs[slot4][ql][j] = tv[n2][j]; pis[slot4][ql][j] = ti[n2][j]; }
    }
    __syncthreads();
    if (tid < 128) {
        float mv[TOPS]; int mi[TOPS];
#pragma unroll
        for (int j = 0; j < TOPS; ++j) { mv[j] = -FLT_MAX; mi[j] = 0; }
#pragma unroll
        for (int sl = 0; sl < 4; ++sl)
#pragma unroll
            for (int j = 0; j < TOPS; ++j) {
                float v = pvs[sl][tid][j]; int c = pis[sl][tid][j];
                if (v > mv[TOPS - 1]) ins4(v, c, mv, mi);
            }
        size_t o = ((size_t)cs * NQ_TOTAL + qt * 128 + tid) * TOPS;
#pragma unroll
        for (int j = 0; j < TOPS; ++j) { pval[o + j] = mv[j]; pidx[o + j] = mi[j]; }
    }
}

// ---------------------------------------------------------------- candidate merge + exact rescore
// one wave per query; 32 candidates (8 slices x top-4) on lanes 0-31;
// 8 rounds of wave-argmax pick approx top-8; exact fp32 rescore picks the winner.
__global__ __launch_bounds__(256) void finalize_q(
        const float* __restrict__ X, const float* __restrict__ ET,
        const float* __restrict__ norms, const float* __restrict__ pval,
        const int* __restrict__ pidx, float* __restrict__ outq,
        float* __restrict__ out_idx_f, float* __restrict__ loss_q,
        int* __restrict__ counts) {
    const int lane = threadIdx.x & 63, w = threadIdx.x >> 6;
    const int q = blockIdx.x * 4 + w;
    float4 x4 = *(const float4*)&X[(size_t)q * DIM + lane * 4];

    // lanes 0-31 -> candidate (slice p = lane>>2, rank j = lane&3)
    float wv = -FLT_MAX;
    int   wc = 0;
    if (lane < 32) {
        size_t off = (((size_t)(lane >> 2) * NQ_TOTAL + q) * TOPS) + (lane & 3);
        wv = pval[off];
        wc = pidx[off];
    }

    int kc[8];
#pragma unroll
    for (int t = 0; t < 8; ++t) {
        float v = wv; int src = lane;
#pragma unroll
        for (int o = 1; o < 64; o <<= 1) {
            float ov = __shfl_xor(v, o); int os = __shfl_xor(src, o);
            bool take = (ov > v) || (ov == v && os < src);
            v = take ? ov : v; src = take ? os : src;
        }
        kc[t] = __shfl(wc, src);
        if (lane == src) wv = -FLT_MAX;     // remove winner
    }

    float sb = -FLT_MAX; int kb = 0; float4 eb = x4;
#pragma unroll
    for (int t = 0; t < 8; ++t) {
        int k = kc[t];
        float4 e4 = *(const float4*)&ET[(size_t)k * DIM + lane * 4];
        float pr = x4.x * e4.x + x4.y * e4.y + x4.z * e4.z + x4.w * e4.w;
#pragma unroll
        for (int o = 1; o < 64; o <<= 1) pr += __shfl_xor(pr, o);
        float s = 2.f * pr - norms[k];
        bool better = (s > sb) || (s == sb && k < kb);
        if (better) { sb = s; kb = k; eb = e4; }
    }
    float4 d4 = {eb.x - x4.x, eb.y - x4.y, eb.z - x4.z, eb.w - x4.w};
    float4 o4 = {x4.x + d4.x, x4.y + d4.y, x4.z + d4.z, x4.w + d4.w};
    *(float4*)&outq[(size_t)q * DIM + lane * 4] = o4;
    float l = d4.x * d4.x + d4.y * d4.y + d4.z * d4.z + d4.w * d4.w;
#pragma unroll
    for (int o = 1; o < 64; o <<= 1) l += __shfl_xor(l, o);
    if (lane == 0) {
        out_idx_f[q] = (float)kb;
        loss_q[q] = l;
        atomicAdd(&counts[kb], 1);
    }
}

// ---------------------------------------------------------------- scalars
__global__ __launch_bounds__(256) void final_scalars(
        const int* __restrict__ counts, const float* __restrict__ loss_q,
        float* __restrict__ out_sc) {
    int t = threadIdx.x;
    float ls = 0.f;
    for (int i = t; i < NQ_TOTAL; i += 256) ls += loss_q[i];
    float ent = 0.f;
    for (int k = t; k < K_CODES; k += 256) {
        float p = (float)counts[k] / (float)NQ_TOTAL;
        ent -= p * logf(p + 1e-10f);
    }
#pragma unroll
    for (int o = 1; o < 64; o <<= 1) { ls += __shfl_xor(ls, o); ent += __shfl_xor(ent, o); }
    __shared__ float rl[4], re[4];
    if ((t & 63) == 0) { rl[t >> 6] = ls; re[t >> 6] = ent; }
    __syncthreads();
    if (t == 0) {
        float L = rl[0] + rl[1] + rl[2] + rl[3];
        float Ee = re[0] + re[1] + re[2] + re[3];
        float mse = L / (float)((size_t)NQ_TOTAL * DIM);
        out_sc[0] = 1.1f * mse;                         // e_latent + 0.1*q_latent
        out_sc[1] = -0.1f * (Ee / logf((float)K_CODES));
    }
}

extern "C" void kernel_launch(void* const* d_in, const int* in_sizes, int n_in,
                              void* d_out, int out_size, void* d_ws, size_t ws_size,
                              hipStream_t stream) {
    const float* X = (const float*)d_in[0];   // [32768, 256] fp32
    const float* E = (const float*)d_in[1];   // [256, 8192]  fp32

    float* out       = (float*)d_out;
    float* outq      = out;                           // 8388608
    float* out_idx_f = out + (size_t)NQ_TOTAL * DIM;  // 32768 (indices as f32)
    float* out_sc    = out_idx_f + NQ_TOTAL;          // 2 scalars

    char* ws = (char*)d_ws;
    int*            counts = (int*)(ws + WS_COUNTS);
    float*          loss_q = (float*)(ws + WS_LOSSQ);
    float*          norms  = (float*)(ws + WS_NORMS);
    float*          pval   = (float*)(ws + WS_PVAL);
    int*            pidx   = (int*)(ws + WS_PIDX);
    float*          ET     = (float*)(ws + WS_ET);
    unsigned short* Ahi    = (unsigned short*)(ws + WS_AHI);
    unsigned short* Bhi    = (unsigned short*)(ws + WS_BHI);

    hipMemsetAsync(counts, 0, K_CODES * sizeof(int), stream);
    norms_kernel<<<K_CODES / 256, 256, 0, stream>>>(E, norms);
    pack_X<<<(NQ_TOTAL * 32) / 256, 256, 0, stream>>>(X, Bhi);
    pack_Bx<<<256, 256, 0, stream>>>(Bhi);
    pack_E<<<(K_CODES * 32) / 256, 256, 0, stream>>>(E, Ahi, ET);
    pack_Ax<<<64, 256, 0, stream>>>(norms, Ahi);
    argmax_mfma<<<dim3(CSPLIT, NQ_TOTAL / 128), 256, 0, stream>>>(Ahi, Bhi, pval, pidx);
    finalize_q<<<NQ_TOTAL / 4, 256, 0, stream>>>(X, ET, norms, pval, pidx, outq, out_idx_f, loss_q, counts);
    final_scalars<<<1, 256, 0, stream>>>(counts, loss_q, out_sc);
}

// Round 7
// 482.236 us; speedup vs baseline: 2.1055x; 1.0708x over previous
//
#include <hip/hip_runtime.h>
#include <cfloat>
#include <cmath>

typedef short short8 __attribute__((ext_vector_type(8)));
typedef unsigned short ushort8 __attribute__((ext_vector_type(8)));
typedef float f32x16 __attribute__((ext_vector_type(16)));

#define K_CODES 8192
#define DIM 256
#define NQ_TOTAL 32768
#define CSPLIT 8
#define NSTAGE 17          /* 16 data stages + 1 norm stage */
#define NSTEP 68           /* 4 double-tiles (256 codes) x 17 stages */
#define PDEPTH 4           /* A-pipeline depth (register slots) */
#define TOPS 4             /* per-slice top-N stored */

/* ws layout (byte offsets) */
#define WS_COUNTS 0          /* int[8192]            32 KB (zeroed) */
#define WS_LOSSQ  32768      /* float[32768]        128 KB */
#define WS_NORMS  163840     /* float[8192]          32 KB */
#define WS_PVAL   196608     /* float[8*32768*4]      4 MB */
#define WS_PIDX   4390912    /* int  [8*32768*4]      4 MB */
#define WS_ET     8585216    /* float[8192*256]       8 MB */
#define WS_AHI    16973824   /* ushort[64*17*4*64*8]  4.25 MB */
#define WS_BHI    21430272   /* ushort[512*17*2*64*8] 17 MB */

__device__ inline unsigned short f32_to_bf16_rne(float x) {
    unsigned u = __builtin_bit_cast(unsigned, x);
    unsigned r = u + 0x7FFFu + ((u >> 16) & 1u);
    return (unsigned short)(r >> 16);
}
__device__ inline float bf16_to_f32(unsigned short hh) {
    unsigned u = ((unsigned)hh) << 16;
    return __builtin_bit_cast(float, u);
}

// sorted-descending top-4 insert with carry-down (caller guards v > tv[3])
__device__ inline void ins4(float v, int c, float* tv, int* ti) {
#pragma unroll
    for (int j = 0; j < TOPS; ++j) {
        bool g = v > tv[j];
        float ov = tv[j]; int oc = ti[j];
        tv[j] = g ? v : ov;  ti[j] = g ? c : oc;
        v = g ? ov : v;      c = g ? oc : c;
    }
}

// ---------------------------------------------------------------- norms (fp32, exact)
__global__ __launch_bounds__(256) void norms_kernel(const float* __restrict__ E,
                                                    float* __restrict__ norms) {
    int k = blockIdx.x * 256 + threadIdx.x;
    float s = 0.f;
#pragma unroll 8
    for (int d = 0; d < DIM; ++d) { float v = E[(size_t)d * K_CODES + k]; s += v * v; }
    norms[k] = s;
}

// ---------------------------------------------------------------- pack X -> frag-linear bf16 (64-query tiles)
__global__ __launch_bounds__(256) void pack_X(const float* __restrict__ X,
                                              unsigned short* __restrict__ Bhi) {
    int id = blockIdx.x * 256 + threadIdx.x;      // 1048576 total
    int q = id >> 5, db = id & 31;
    const float* src = X + (size_t)q * DIM + db * 8;
    float4 a = *(const float4*)src, b = *(const float4*)(src + 4);
    float xs[8] = {a.x, a.y, a.z, a.w, b.x, b.y, b.z, b.w};
    ushort8 vh;
#pragma unroll
    for (int i = 0; i < 8; ++i) vh[i] = f32_to_bf16_rne(xs[i]);
    int qt = q >> 6, nt = (q >> 5) & 1, lq = q & 31, s = db >> 1, hh = db & 1;
    int lane = lq + 32 * hh;
    size_t chunk = ((((size_t)qt * NSTAGE + s) * 2 + nt) * 64 + lane) * 8;
    *(ushort8*)&Bhi[chunk] = vh;
}

// ---------------------------------------------------------------- B norm-stage: -0.5 at k=0,1
__global__ __launch_bounds__(256) void pack_Bx(unsigned short* __restrict__ Bhi) {
    int id = blockIdx.x * 256 + threadIdx.x;      // 65536 total
    int lane = id & 63, nt = (id >> 6) & 1, qt = id >> 7;
    ushort8 v = {0, 0, 0, 0, 0, 0, 0, 0};
    if (lane < 32) { v[0] = 0xBF00; v[1] = 0xBF00; }   // bf16(-0.5)
    size_t chunk = ((((size_t)qt * NSTAGE + 16) * 2 + nt) * 64 + lane) * 8;
    *(ushort8*)&Bhi[chunk] = v;
}

// ---------------------------------------------------------------- pack E -> A frags + fp32 E^T
__global__ __launch_bounds__(256) void pack_E(const float* __restrict__ E,
                                              unsigned short* __restrict__ Ahi,
                                              float* __restrict__ ET) {
    int id = blockIdx.x * 256 + threadIdx.x;      // 262144 total
    int db = id >> 13, c = id & 8191;
    float xs[8];
#pragma unroll
    for (int j = 0; j < 8; ++j) xs[j] = E[(size_t)(db * 8 + j) * K_CODES + c];
    float4 f0 = {xs[0], xs[1], xs[2], xs[3]}, f1 = {xs[4], xs[5], xs[6], xs[7]};
    *(float4*)&ET[(size_t)c * DIM + db * 8]     = f0;
    *(float4*)&ET[(size_t)c * DIM + db * 8 + 4] = f1;
    ushort8 vh;
#pragma unroll
    for (int j = 0; j < 8; ++j) vh[j] = f32_to_bf16_rne(xs[j]);
    int ct = c >> 7, mt = (c >> 5) & 3, lc = c & 31, s = db >> 1, hh = db & 1;
    int lane = lc + 32 * hh;
    size_t chunk = ((((size_t)ct * NSTAGE + s) * 4 + mt) * 64 + lane) * 8;
    *(ushort8*)&Ahi[chunk] = vh;
}

// ---------------------------------------------------------------- A norm-stage: nrm_hi, nrm_lo at k=0,1
__global__ __launch_bounds__(256) void pack_Ax(const float* __restrict__ norms,
                                               unsigned short* __restrict__ Ahi) {
    int id = blockIdx.x * 256 + threadIdx.x;      // 16384 total
    int lane = id & 63, mt = (id >> 6) & 3, ct = id >> 8;
    ushort8 v = {0, 0, 0, 0, 0, 0, 0, 0};
    if (lane < 32) {
        float nrm = norms[ct * 128 + mt * 32 + lane];
        unsigned short hi = f32_to_bf16_rne(nrm);
        unsigned short lo = f32_to_bf16_rne(nrm - bf16_to_f32(hi));
        v[0] = hi; v[1] = lo;
    }
    size_t chunk = ((((size_t)ct * NSTAGE + 16) * 4 + mt) * 64 + lane) * 8;
    *(ushort8*)&Ahi[chunk] = v;
}

// ---------------------------------------------------------------- MFMA argmax — barrier-free K-loop
// grid (CSPLIT, 512 query-tiles), 256 threads = 4 waves, wave tile 64 codes x 64 queries.
// Block tile per step: 256 codes x 64 queries (wave w: tile-half th=w>>1, chunk pair wm=w&1).
// B (64 queries, 17 stages) persistent in 34 KB LDS -> 4 blocks/CU; A streams
// global->VGPR via depth-4 rolling pipeline; zero-C MFMA on stage 0 (no acc clears);
// norms folded by stage 16; acc = score/2.
__global__ __launch_bounds__(256, 4) void argmax_mfma(
        const unsigned short* __restrict__ Ahi, const unsigned short* __restrict__ Bhi,
        float* __restrict__ pval, int* __restrict__ pidx) {
    __shared__ __align__(16) char smem[34816];                 // B: 17*2*512 shorts
    unsigned short* Bs = (unsigned short*)smem;
    float (*pvs)[64][TOPS] = (float (*)[64][TOPS])smem;        // merge unions into B region
    int   (*pis)[64][TOPS] = (int (*)[64][TOPS])(smem + 8192);

    const int tid = threadIdx.x;
    const int lane = tid & 63, w = tid >> 6;
    const int th = w >> 1, wm = w & 1;             // tile-half, chunk-pair
    const int h = lane >> 5;
    const int cs = blockIdx.x, qt = blockIdx.y;

    // ---- stage B once: 34 x 1KB chunks (wave-strided)
#pragma unroll
    for (int i = 0; i < 9; ++i) {
        const int g = w + 4 * i;
        if (g < 34) {
            const unsigned short* src = Bhi + (((size_t)qt * 34 + g) * 64 + lane) * 8;
            __builtin_amdgcn_global_load_lds(
                (const __attribute__((address_space(1))) unsigned int*)src,
                (__attribute__((address_space(3))) unsigned int*)(Bs + g * 512), 16, 0, 0);
        }
    }

    // A stream for this wave: step t -> tile (cs*8 + (t/17)*2 + th), stage t%17, chunks wm*2,+1
    const unsigned short* Ab = Ahi + (((size_t)wm * 2) * 64 + lane) * 8;
#define A_OFF(t) ((((size_t)(cs * 8 + ((t) / NSTAGE) * 2 + th) * NSTAGE + ((t) % NSTAGE)) * 4) * 512)

    // prime the A register pipeline (in flight during B staging)
    short8 ap[PDEPTH][2];
#pragma unroll
    for (int p = 0; p < PDEPTH; ++p) {
        ap[p][0] = *(const short8*)(Ab + A_OFF(p));
        ap[p][1] = *(const short8*)(Ab + A_OFF(p) + 512);
    }
    __syncthreads();                               // B visible (drains prime loads too; one-time)

    float tv[2][TOPS]; int ti[2][TOPS];
#pragma unroll
    for (int n2 = 0; n2 < 2; ++n2)
#pragma unroll
        for (int j = 0; j < TOPS; ++j) { tv[n2][j] = -FLT_MAX; ti[n2][j] = 0; }

    f32x16 zc;
#pragma unroll
    for (int r = 0; r < 16; ++r) zc[r] = 0.f;
    f32x16 acc[2][2];

#pragma unroll
    for (int t = 0; t < NSTEP; ++t) {
        const int s = t % NSTAGE, slot = t % PDEPTH;
        short8 a0 = ap[slot][0], a1 = ap[slot][1];
        if (t + PDEPTH < NSTEP) {                  // refill slot for step t+4
            ap[slot][0] = *(const short8*)(Ab + A_OFF(t + PDEPTH));
            ap[slot][1] = *(const short8*)(Ab + A_OFF(t + PDEPTH) + 512);
        }
        short8 b0 = *(const short8*)&Bs[(s * 2 + 0) * 512 + lane * 8];
        short8 b1 = *(const short8*)&Bs[(s * 2 + 1) * 512 + lane * 8];
        if (s == 0) {                              // zero-C MFMA: no explicit acc clears
            acc[0][0] = __builtin_amdgcn_mfma_f32_32x32x16_bf16(a0, b0, zc, 0, 0, 0);
            acc[0][1] = __builtin_amdgcn_mfma_f32_32x32x16_bf16(a0, b1, zc, 0, 0, 0);
            acc[1][0] = __builtin_amdgcn_mfma_f32_32x32x16_bf16(a1, b0, zc, 0, 0, 0);
            acc[1][1] = __builtin_amdgcn_mfma_f32_32x32x16_bf16(a1, b1, zc, 0, 0, 0);
        } else {
            acc[0][0] = __builtin_amdgcn_mfma_f32_32x32x16_bf16(a0, b0, acc[0][0], 0, 0, 0);
            acc[0][1] = __builtin_amdgcn_mfma_f32_32x32x16_bf16(a0, b1, acc[0][1], 0, 0, 0);
            acc[1][0] = __builtin_amdgcn_mfma_f32_32x32x16_bf16(a1, b0, acc[1][0], 0, 0, 0);
            acc[1][1] = __builtin_amdgcn_mfma_f32_32x32x16_bf16(a1, b1, acc[1][1], 0, 0, 0);
        }

        if (s == NSTAGE - 1) {                     // tile done: acc = score/2, norms folded
            const int cbase = (cs * 8 + (t / NSTAGE) * 2 + th) * 128 + wm * 64;
#pragma unroll
            for (int mt = 0; mt < 2; ++mt) {
                const int cb0 = cbase + mt * 32 + 4 * h;
#pragma unroll
                for (int r = 0; r < 16; ++r) {
                    const int code = cb0 + (r & 3) + 8 * (r >> 2);
#pragma unroll
                    for (int n2 = 0; n2 < 2; ++n2) {
                        float v = acc[mt][n2][r];
                        if (v > tv[n2][TOPS - 1]) ins4(v, code, tv[n2], ti[n2]);
                    }
                }
            }
        }
    }
#undef A_OFF

    __syncthreads();                               // all B reads done before merge aliases B
    const int slot8 = w * 2 + h;                   // 8 cells per query column
#pragma unroll
    for (int n2 = 0; n2 < 2; ++n2) {
        const int ql = n2 * 32 + (lane & 31);
#pragma unroll
        for (int j = 0; j < TOPS; ++j) { pvs[slot8][ql][j] = tv[n2][j]; pis[slot8][ql][j] = ti[n2][j]; }
    }
    __syncthreads();
    if (tid < 64) {
        float mv[TOPS]; int mi[TOPS];
#pragma unroll
        for (int j = 0; j < TOPS; ++j) { mv[j] = -FLT_MAX; mi[j] = 0; }
#pragma unroll
        for (int sl = 0; sl < 8; ++sl)
#pragma unroll
            for (int j = 0; j < TOPS; ++j) {
                float v = pvs[sl][tid][j]; int c = pis[sl][tid][j];
                if (v > mv[TOPS - 1]) ins4(v, c, mv, mi);
            }
        size_t o = ((size_t)cs * NQ_TOTAL + qt * 64 + tid) * TOPS;
#pragma unroll
        for (int j = 0; j < TOPS; ++j) { pval[o + j] = mv[j]; pidx[o + j] = mi[j]; }
    }
}

// ---------------------------------------------------------------- candidate merge + exact rescore
// one wave per query; 32 candidates (8 slices x top-4) on lanes 0-31;
// 8 rounds of wave-argmax pick approx top-8; exact fp32 rescore picks the winner.
__global__ __launch_bounds__(256) void finalize_q(
        const float* __restrict__ X, const float* __restrict__ ET,
        const float* __restrict__ norms, const float* __restrict__ pval,
        const int* __restrict__ pidx, float* __restrict__ outq,
        float* __restrict__ out_idx_f, float* __restrict__ loss_q,
        int* __restrict__ counts) {
    const int lane = threadIdx.x & 63, w = threadIdx.x >> 6;
    const int q = blockIdx.x * 4 + w;
    float4 x4 = *(const float4*)&X[(size_t)q * DIM + lane * 4];

    // lanes 0-31 -> candidate (slice p = lane>>2, rank j = lane&3)
    float wv = -FLT_MAX;
    int   wc = 0;
    if (lane < 32) {
        size_t off = (((size_t)(lane >> 2) * NQ_TOTAL + q) * TOPS) + (lane & 3);
        wv = pval[off];
        wc = pidx[off];
    }

    int kc[8];
#pragma unroll
    for (int t = 0; t < 8; ++t) {
        float v = wv; int src = lane;
#pragma unroll
        for (int o = 1; o < 64; o <<= 1) {
            float ov = __shfl_xor(v, o); int os = __shfl_xor(src, o);
            bool take = (ov > v) || (ov == v && os < src);
            v = take ? ov : v; src = take ? os : src;
        }
        kc[t] = __shfl(wc, src);
        if (lane == src) wv = -FLT_MAX;     // remove winner
    }

    float sb = -FLT_MAX; int kb = 0; float4 eb = x4;
#pragma unroll
    for (int t = 0; t < 8; ++t) {
        int k = kc[t];
        float4 e4 = *(const float4*)&ET[(size_t)k * DIM + lane * 4];
        float pr = x4.x * e4.x + x4.y * e4.y + x4.z * e4.z + x4.w * e4.w;
#pragma unroll
        for (int o = 1; o < 64; o <<= 1) pr += __shfl_xor(pr, o);
        float s = 2.f * pr - norms[k];
        bool better = (s > sb) || (s == sb && k < kb);
        if (better) { sb = s; kb = k; eb = e4; }
    }
    float4 d4 = {eb.x - x4.x, eb.y - x4.y, eb.z - x4.z, eb.w - x4.w};
    float4 o4 = {x4.x + d4.x, x4.y + d4.y, x4.z + d4.z, x4.w + d4.w};
    *(float4*)&outq[(size_t)q * DIM + lane * 4] = o4;
    float l = d4.x * d4.x + d4.y * d4.y + d4.z * d4.z + d4.w * d4.w;
#pragma unroll
    for (int o = 1; o < 64; o <<= 1) l += __shfl_xor(l, o);
    if (lane == 0) {
        out_idx_f[q] = (float)kb;
        loss_q[q] = l;
        atomicAdd(&counts[kb], 1);
    }
}

// ---------------------------------------------------------------- scalars
__global__ __launch_bounds__(256) void final_scalars(
        const int* __restrict__ counts, const float* __restrict__ loss_q,
        float* __restrict__ out_sc) {
    int t = threadIdx.x;
    float ls = 0.f;
    for (int i = t; i < NQ_TOTAL; i += 256) ls += loss_q[i];
    float ent = 0.f;
    for (int k = t; k < K_CODES; k += 256) {
        float p = (float)counts[k] / (float)NQ_TOTAL;
        ent -= p * logf(p + 1e-10f);
    }
#pragma unroll
    for (int o = 1; o < 64; o <<= 1) { ls += __shfl_xor(ls, o); ent += __shfl_xor(ent, o); }
    __shared__ float rl[4], re[4];
    if ((t & 63) == 0) { rl[t >> 6] = ls; re[t >> 6] = ent; }
    __syncthreads();
    if (t == 0) {
        float L = rl[0] + rl[1] + rl[2] + rl[3];
        float Ee = re[0] + re[1] + re[2] + re[3];
        float mse = L / (float)((size_t)NQ_TOTAL * DIM);
        out_sc[0] = 1.1f * mse;                         // e_latent + 0.1*q_latent
        out_sc[1] = -0.1f * (Ee / logf((float)K_CODES));
    }
}

extern "C" void kernel_launch(void* const* d_in, const int* in_sizes, int n_in,
                              void* d_out, int out_size, void* d_ws, size_t ws_size,
                              hipStream_t stream) {
    const float* X = (const float*)d_in[0];   // [32768, 256] fp32
    const float* E = (const float*)d_in[1];   // [256, 8192]  fp32

    float* out       = (float*)d_out;
    float* outq      = out;                           // 8388608
    float* out_idx_f = out + (size_t)NQ_TOTAL * DIM;  // 32768 (indices as f32)
    float* out_sc    = out_idx_f + NQ_TOTAL;          // 2 scalars

    char* ws = (char*)d_ws;
    int*            counts = (int*)(ws + WS_COUNTS);
    float*          loss_q = (float*)(ws + WS_LOSSQ);
    float*          norms  = (float*)(ws + WS_NORMS);
    float*          pval   = (float*)(ws + WS_PVAL);
    int*            pidx   = (int*)(ws + WS_PIDX);
    float*          ET     = (float*)(ws + WS_ET);
    unsigned short* Ahi    = (unsigned short*)(ws + WS_AHI);
    unsigned short* Bhi    = (unsigned short*)(ws + WS_BHI);

    hipMemsetAsync(counts, 0, K_CODES * sizeof(int), stream);
    norms_kernel<<<K_CODES / 256, 256, 0, stream>>>(E, norms);
    pack_X<<<(NQ_TOTAL * 32) / 256, 256, 0, stream>>>(X, Bhi);
    pack_Bx<<<256, 256, 0, stream>>>(Bhi);
    pack_E<<<(K_CODES * 32) / 256, 256, 0, stream>>>(E, Ahi, ET);
    pack_Ax<<<64, 256, 0, stream>>>(norms, Ahi);
    argmax_mfma<<<dim3(CSPLIT, NQ_TOTAL / 64), 256, 0, stream>>>(Ahi, Bhi, pval, pidx);
    finalize_q<<<NQ_TOTAL / 4, 256, 0, stream>>>(X, ET, norms, pval, pidx, outq, out_idx_f, loss_q, counts);
    final_scalars<<<1, 256, 0, stream>>>(counts, loss_q, out_sc);
}